// Round 6
// baseline (137.170 us; speedup 1.0000x reference)
//
#include <hip/hip_runtime.h>

typedef _Float16 half8 __attribute__((ext_vector_type(8)));
typedef _Float16 half4_t __attribute__((ext_vector_type(4)));
typedef __fp16 fp16x2 __attribute__((ext_vector_type(2)));
typedef float float4_t __attribute__((ext_vector_type(4)));
typedef float float2_t __attribute__((ext_vector_type(2)));

#define SB 32            // samples per block (small block -> 6 blocks/CU)
#define NT 256           // threads per block (4 waves, each M32 x N32)
#define RS (SB * 8)      // chunk-row stride in fp16 elems (256)

// d_ws fp16 element offsets (weights, MFMA-chunk-major, pre-scaled)
#define OFF_W1   0       // [128][32] chunk-major, k>=6 zero-padded, x2log2e
#define OFF_W21  4096
#define OFF_W22  20480
#define OFF_WM1  36864
#define OFF_WM2  53248
#define OFF_W4A  69632   // L4 A-frags: chain0=w31 (raw), chain1=w32 x(-log2e)
#define OFF_BIAS 73728   // fp32[640]: b1..bm2, all x2log2e
#define WS_HELEMS 73728

#define SCL_TANH 2.8853900817779268f   // 2*log2(e)
#define SCL_SIG  -1.4426950408889634f  // -log2(e)

// input already scaled by 2log2e: tanh = 1 - 2/(1+exp2(a))
__device__ __forceinline__ float tanh_pre(float a) {
  float e = __builtin_amdgcn_exp2f(a);
  return fmaf(-2.f, __builtin_amdgcn_rcpf(1.f + e), 1.f);
}
__device__ __forceinline__ half4_t pack4(float v0, float v1, float v2, float v3) {
  fp16x2 lo = __builtin_amdgcn_cvt_pkrtz(v0, v1);
  fp16x2 hi = __builtin_amdgcn_cvt_pkrtz(v2, v3);
  half4_t h;
  h[0] = (_Float16)lo[0]; h[1] = (_Float16)lo[1];
  h[2] = (_Float16)hi[0]; h[3] = (_Float16)hi[1];
  return h;
}

__global__ void prepack(const float* __restrict__ w1, const float* __restrict__ w21,
                        const float* __restrict__ w22, const float* __restrict__ wm1,
                        const float* __restrict__ wm2, const float* __restrict__ w31,
                        const float* __restrict__ w32, const float* __restrict__ b1,
                        const float* __restrict__ b21, const float* __restrict__ b22,
                        const float* __restrict__ bm1, const float* __restrict__ bm2,
                        _Float16* __restrict__ ws) {
  const int stride = gridDim.x * blockDim.x;
  for (int i = blockIdx.x * blockDim.x + threadIdx.x; i < WS_HELEMS; i += stride) {
    float v;
    if (i < OFF_W21) {                       // W1: [128][32] chunk-major, KC=4
      int t = i;
      int j = t & 7, c = t >> 3, l16 = c & 15, t1 = c >> 4;
      int k8 = t1 & 3, mt = t1 >> 2;
      int row = mt * 16 + l16, k = k8 * 8 + j;
      v = (k < 6) ? w1[row * 6 + k] * SCL_TANH : 0.f;
    } else if (i < OFF_W4A) {                // four 128x128 chunk-major, KC=16
      int t = i - OFF_W21;
      int m = t >> 14; t &= 16383;
      const float* src = (m == 0) ? w21 : (m == 1) ? w22 : (m == 2) ? wm1 : wm2;
      int j = t & 7, c = t >> 3, l16 = c & 15, t1 = c >> 4;
      int k8 = t1 & 15, mt = t1 >> 4;
      v = src[(mt * 16 + l16) * 128 + k8 * 8 + j] * SCL_TANH;
    } else {                                 // L4 A-frags, 2 chains
      int t = i - OFF_W4A;
      int j = t & 7, r = t >> 3, l16 = r & 15, q = r >> 4;
      int cc = q & 15, chain = q >> 4;
      int k = cc * 8 + j, m = l16;
      if (chain == 0) v = (m < 3) ? w31[m * 128 + k] : 0.f;
      else            v = (m < 2) ? w32[m * 128 + k] * SCL_SIG : 0.f;
    }
    ws[i] = (_Float16)v;
  }
  float* bws = (float*)(ws + OFF_BIAS);
  for (int i = blockIdx.x * blockDim.x + threadIdx.x; i < 640; i += stride) {
    int layer = i >> 7, idx = i & 127;
    const float* src = (layer == 0) ? b1 : (layer == 1) ? b21
                     : (layer == 2) ? b22 : (layer == 3) ? bm1 : bm2;
    bws[i] = src[idx] * SCL_TANH;
  }
}

// M32xN32 layer tile: wave owns 2 m-tiles (features [32wv,32wv+32)) x both
// n-tiles of the 32-sample block. B-frags reused across both m-tiles.
// Bias added post-MFMA; tanh fused; chunk-major LDS (RS=256).
__device__ __forceinline__ void layer2x2(const _Float16* __restrict__ wA,
                                         const float* __restrict__ bb,
                                         const _Float16* __restrict__ inB,
                                         _Float16* __restrict__ outB,
                                         int mg, int quad, int l16) {
  const int mt0 = mg * 2;
  half8 A[2][4];
#pragma unroll
  for (int mi = 0; mi < 2; ++mi)
#pragma unroll
    for (int kk = 0; kk < 4; ++kk)
      A[mi][kk] = *(const half8*)(wA + (((mt0 + mi) * 16 + kk * 4 + quad) * 16 + l16) * 8);
  float4_t bv[2];
  bv[0] = *(const float4_t*)(bb + (mt0 + 0) * 16 + quad * 4);
  bv[1] = *(const float4_t*)(bb + (mt0 + 1) * 16 + quad * 4);

  float4_t acc[2][2];
#pragma unroll
  for (int mi = 0; mi < 2; ++mi)
#pragma unroll
    for (int ni = 0; ni < 2; ++ni)
      acc[mi][ni] = (float4_t){0.f, 0.f, 0.f, 0.f};

#pragma unroll
  for (int ni = 0; ni < 2; ++ni) {
    half8 B[4];
#pragma unroll
    for (int kk = 0; kk < 4; ++kk)
      B[kk] = *(const half8*)(inB + (kk * 4 + quad) * RS + (ni * 16 + l16) * 8);
#pragma unroll
    for (int kk = 0; kk < 4; ++kk) {
      acc[0][ni] = __builtin_amdgcn_mfma_f32_16x16x32_f16(A[0][kk], B[kk], acc[0][ni], 0, 0, 0);
      acc[1][ni] = __builtin_amdgcn_mfma_f32_16x16x32_f16(A[1][kk], B[kk], acc[1][ni], 0, 0, 0);
    }
  }

#pragma unroll
  for (int mi = 0; mi < 2; ++mi) {
    const int ob = (mt0 + mi) * 16 + quad * 4;
    _Float16* base = outB + (ob >> 3) * RS + (ob & 7);
#pragma unroll
    for (int ni = 0; ni < 2; ++ni) {
      const int s = ni * 16 + l16;
      float4_t a = acc[mi][ni];
      half4_t h = pack4(tanh_pre(a[0] + bv[mi][0]), tanh_pre(a[1] + bv[mi][1]),
                        tanh_pre(a[2] + bv[mi][2]), tanh_pre(a[3] + bv[mi][3]));
      *(half4_t*)(base + s * 8) = h;
    }
  }
}

// Small-block variant of the proven 3-buffer / 5-phase schedule:
// SB=32, NT=256 (4 waves), LDS 24 KiB -> 6 blocks/CU (24 waves, 75% cap).
// Barriers sync only 4 waves; 6 desynced blocks/CU fill each other's
// MFMA/tanh/LDS bubbles. __launch_bounds__(256,6): 6 blocks/CU -> 6
// waves/SIMD -> ~85-VGPR budget (kernel needs ~48; R1 lesson).
__global__ __launch_bounds__(NT, 6) void bnet_main(
    const float* __restrict__ x, const float* __restrict__ meang,
    const float* __restrict__ stdg, const float* __restrict__ b31,
    const float* __restrict__ b32, const _Float16* __restrict__ ws,
    float* __restrict__ out) {
  __shared__ __align__(16) _Float16 bufH[SB * 128];
  __shared__ __align__(16) _Float16 bufA[SB * 128];
  __shared__ __align__(16) _Float16 bufB[SB * 128];

  const int tid = threadIdx.x;
  const int wv = tid >> 6;          // 0..3 = m-group: features [32wv, 32wv+32)
  const int lane = tid & 63;
  const int quad = lane >> 4;
  const int l16 = lane & 15;
  const int s0 = blockIdx.x * SB;
  const float* biasF = (const float*)(ws + OFF_BIAS);

  // ---- L1: B built from global x (K=32 zero-padded), 2x2 tiles ----
  {
    half8 A1[2];
#pragma unroll
    for (int mi = 0; mi < 2; ++mi)
      A1[mi] = *(const half8*)(ws + OFF_W1 + (((wv * 2 + mi) * 4 + quad) * 16 + l16) * 8);
    float4_t bv1[2];
    bv1[0] = *(const float4_t*)(biasF + (wv * 2 + 0) * 16 + quad * 4);
    bv1[1] = *(const float4_t*)(biasF + (wv * 2 + 1) * 16 + quad * 4);

    half8 xb[2];
#pragma unroll
    for (int ni = 0; ni < 2; ++ni) {
#pragma unroll
      for (int j = 0; j < 8; ++j) xb[ni][j] = (_Float16)0.f;
      if (quad == 0) {
        const float* xp = x + (size_t)(s0 + ni * 16 + l16) * 6;
        float2_t e0 = *(const float2_t*)(xp);
        float2_t e1 = *(const float2_t*)(xp + 2);
        float2_t e2 = *(const float2_t*)(xp + 4);
        xb[ni][0] = (_Float16)e0[0]; xb[ni][1] = (_Float16)e0[1];
        xb[ni][2] = (_Float16)e1[0]; xb[ni][3] = (_Float16)e1[1];
        xb[ni][4] = (_Float16)e2[0]; xb[ni][5] = (_Float16)e2[1];
      }
    }
    float4_t acc[2][2];
#pragma unroll
    for (int mi = 0; mi < 2; ++mi)
#pragma unroll
      for (int ni = 0; ni < 2; ++ni) {
        acc[mi][ni] = (float4_t){0.f, 0.f, 0.f, 0.f};
        acc[mi][ni] = __builtin_amdgcn_mfma_f32_16x16x32_f16(A1[mi], xb[ni], acc[mi][ni], 0, 0, 0);
      }
#pragma unroll
    for (int mi = 0; mi < 2; ++mi) {
      const int ob = (wv * 2 + mi) * 16 + quad * 4;
      _Float16* base = bufH + (ob >> 3) * RS + (ob & 7);
#pragma unroll
      for (int ni = 0; ni < 2; ++ni) {
        const int s = ni * 16 + l16;
        float4_t a = acc[mi][ni];
        half4_t h = pack4(tanh_pre(a[0] + bv1[mi][0]), tanh_pre(a[1] + bv1[mi][1]),
                          tanh_pre(a[2] + bv1[mi][2]), tanh_pre(a[3] + bv1[mi][3]));
        *(half4_t*)(base + s * 8) = h;
      }
    }
  }
  __syncthreads();                                           // b1

  layer2x2(ws + OFF_W21, biasF + 128, bufH, bufA, wv, quad, l16);  // x21: H -> A
  layer2x2(ws + OFF_W22, biasF + 256, bufH, bufB, wv, quad, l16);  // x22: H -> B
  __syncthreads();                                           // b2 (H reads done)

  layer2x2(ws + OFF_WM1, biasF + 384, bufA, bufH, wv, quad, l16);  // xm1: A -> H
  half8 A4[2][4];                                            // prefetch L4 (waves 0-1)
  if (wv < 2) {
#pragma unroll
    for (int c = 0; c < 2; ++c)
#pragma unroll
      for (int kk = 0; kk < 4; ++kk)
        A4[c][kk] = *(const half8*)(ws + OFF_W4A +
                                    ((c * 16 + kk * 4 + quad) * 16 + l16) * 8);
  }
  __syncthreads();                                           // b3 (A reads done)

  layer2x2(ws + OFF_WM2, biasF + 512, bufB, bufA, wv, quad, l16);  // xm2: B -> A
  __syncthreads();                                           // b4

  // ---- L4 + QP epilogue: waves 0-1, one 16-sample n-tile each, both chains ----
  if (wv < 2) {
    const int nt = wv;
    float4_t c0 = (float4_t){0.f, 0.f, 0.f, 0.f};
    float4_t c1 = (float4_t){0.f, 0.f, 0.f, 0.f};
    if (quad == 0) {
      c0[0] = b31[0]; c0[1] = b31[1]; c0[2] = b31[2];
      c1[0] = b32[0] * SCL_SIG; c1[1] = b32[1] * SCL_SIG;
    }
#pragma unroll
    for (int kk = 0; kk < 4; ++kk) {
      half8 bh = *(const half8*)(bufH + (kk * 4 + quad) * RS + (nt * 16 + l16) * 8);
      half8 bc = *(const half8*)(bufA + (kk * 4 + quad) * RS + (nt * 16 + l16) * 8);
      c0 = __builtin_amdgcn_mfma_f32_16x16x32_f16(A4[0][kk], bh, c0, 0, 0, 0);
      c1 = __builtin_amdgcn_mfma_f32_16x16x32_f16(A4[1][kk], bc, c1, 0, 0, 0);
    }
    if (quad == 0) {   // rows 0..3 live in lanes 0-15, regs 0-3
      const int s = nt * 16 + l16;
      float u0 = -c0[0];
      float u1 = -c0[1];
      float u2 = -c0[2];
      float p0 = 4.f * __builtin_amdgcn_rcpf(1.f + __builtin_amdgcn_exp2f(c1[0]));
      float p1 = 4.f * __builtin_amdgcn_rcpf(1.f + __builtin_amdgcn_exp2f(c1[1]));
      const float m0 = meang[0], m1 = meang[1], m2 = meang[2];
      const float m3 = meang[3], m4 = meang[4], m5 = meang[5];
      const float sd0 = stdg[0], sd1 = stdg[1], sd2 = stdg[2];
      const float sd3 = stdg[3], sd4 = stdg[4], sd5 = stdg[5];
      const float* xp = x + (size_t)(s0 + s) * 6;
      float2_t e0 = *(const float2_t*)(xp);
      float2_t e1 = *(const float2_t*)(xp + 2);
      float2_t e2 = *(const float2_t*)(xp + 4);
      float px = e0[0] * sd0 + m0, vx = e0[1] * sd1 + m1;
      float py = e1[0] * sd2 + m2, vy = e1[1] * sd3 + m3;
      float pz = e2[0] * sd4 + m4, vz = e2[1] * sd5 + m5;
      float dx = px - 10.f, dy = py - 10.f, dz = pz - 9.f;
      float dx2 = dx * dx, dy2 = dy * dy, dz2 = dz * dz;
      float dx3 = dx2 * dx, dy3 = dy2 * dy, dz3 = dz2 * dz;
      float barrier = dx3 * dx + dy3 * dy + dz3 * dz - 2401.f;  // R^4
      float bdot = 4.f * (dx3 * vx + dy3 * vy + dz3 * vz);
      float Lf2b = 12.f * (dx2 * vx * vx + dy2 * vy * vy + dz2 * vz * vz);
      float g0 = -4.f * dx3, g1 = -4.f * dy3, g2 = -4.f * dz3;
      float hv = Lf2b + (p0 + p1) * bdot + p0 * p1 * barrier;
      float Gu = g0 * u0 + g1 * u1 + g2 * u2;
      float GG = g0 * g0 + g1 * g1 + g2 * g2;
      float lam = fmaxf(Gu - hv, 0.f) / GG;
      float* op = out + (size_t)(s0 + s) * 3;
      op[0] = u0 - lam * g0;
      op[1] = u1 - lam * g1;
      op[2] = u2 - lam * g2;
    }
  }
}

extern "C" void kernel_launch(void* const* d_in, const int* in_sizes, int n_in,
                              void* d_out, int out_size, void* d_ws, size_t ws_size,
                              hipStream_t stream) {
  const float* x    = (const float*)d_in[0];
  const float* mean = (const float*)d_in[1];
  const float* stdv = (const float*)d_in[2];
  const float* w1   = (const float*)d_in[3];
  const float* b1   = (const float*)d_in[4];
  const float* w21  = (const float*)d_in[5];
  const float* b21  = (const float*)d_in[6];
  const float* w22  = (const float*)d_in[7];
  const float* b22  = (const float*)d_in[8];
  const float* wm1  = (const float*)d_in[9];
  const float* bm1  = (const float*)d_in[10];
  const float* wm2  = (const float*)d_in[11];
  const float* bm2  = (const float*)d_in[12];
  const float* w31  = (const float*)d_in[13];
  const float* b31  = (const float*)d_in[14];
  const float* w32  = (const float*)d_in[15];
  const float* b32  = (const float*)d_in[16];
  _Float16* ws = (_Float16*)d_ws;
  float* out = (float*)d_out;
  const int batch = in_sizes[0] / 6;

  hipLaunchKernelGGL(prepack, dim3(96), dim3(256), 0, stream,
                     w1, w21, w22, wm1, wm2, w31, w32,
                     b1, b21, b22, bm1, bm2, ws);
  hipLaunchKernelGGL(bnet_main, dim3(batch / SB), dim3(NT), 0, stream,
                     x, mean, stdv, b31, b32, (const _Float16*)ws, out);
}

// Round 7
// 125.408 us; speedup vs baseline: 1.0938x; 1.0938x over previous
//
#include <hip/hip_runtime.h>

typedef _Float16 half8 __attribute__((ext_vector_type(8)));
typedef _Float16 half4_t __attribute__((ext_vector_type(4)));
typedef __fp16 fp16x2 __attribute__((ext_vector_type(2)));
typedef float float4_t __attribute__((ext_vector_type(4)));
typedef float float2_t __attribute__((ext_vector_type(2)));

#define SB 32            // samples per block (small block -> 6 blocks/CU by LDS)
#define NT 256           // threads per block (4 waves, each M32 x N32)
#define RS (SB * 8)      // chunk-row stride in fp16 elems (256)

// d_ws fp16 element offsets (weights, MFMA-chunk-major, pre-scaled)
#define OFF_W1   0       // [128][32] chunk-major, k>=6 zero-padded, x2log2e
#define OFF_W21  4096
#define OFF_W22  20480
#define OFF_WM1  36864
#define OFF_WM2  53248
#define OFF_W4A  69632   // L4 A-frags: chain0=w31 (raw), chain1=w32 x(-log2e)
#define OFF_BIAS 73728   // fp32[640]: b1..bm2, all x2log2e
#define WS_HELEMS 73728

#define SCL_TANH 2.8853900817779268f   // 2*log2(e)
#define SCL_SIG  -1.4426950408889634f  // -log2(e)

// input already scaled by 2log2e: tanh = 1 - 2/(1+exp2(a))
__device__ __forceinline__ float tanh_pre(float a) {
  float e = __builtin_amdgcn_exp2f(a);
  return fmaf(-2.f, __builtin_amdgcn_rcpf(1.f + e), 1.f);
}
__device__ __forceinline__ half4_t pack4(float v0, float v1, float v2, float v3) {
  fp16x2 lo = __builtin_amdgcn_cvt_pkrtz(v0, v1);
  fp16x2 hi = __builtin_amdgcn_cvt_pkrtz(v2, v3);
  half4_t h;
  h[0] = (_Float16)lo[0]; h[1] = (_Float16)lo[1];
  h[2] = (_Float16)hi[0]; h[3] = (_Float16)hi[1];
  return h;
}

__global__ void prepack(const float* __restrict__ w1, const float* __restrict__ w21,
                        const float* __restrict__ w22, const float* __restrict__ wm1,
                        const float* __restrict__ wm2, const float* __restrict__ w31,
                        const float* __restrict__ w32, const float* __restrict__ b1,
                        const float* __restrict__ b21, const float* __restrict__ b22,
                        const float* __restrict__ bm1, const float* __restrict__ bm2,
                        _Float16* __restrict__ ws) {
  const int stride = gridDim.x * blockDim.x;
  for (int i = blockIdx.x * blockDim.x + threadIdx.x; i < WS_HELEMS; i += stride) {
    float v;
    if (i < OFF_W21) {                       // W1: [128][32] chunk-major, KC=4
      int t = i;
      int j = t & 7, c = t >> 3, l16 = c & 15, t1 = c >> 4;
      int k8 = t1 & 3, mt = t1 >> 2;
      int row = mt * 16 + l16, k = k8 * 8 + j;
      v = (k < 6) ? w1[row * 6 + k] * SCL_TANH : 0.f;
    } else if (i < OFF_W4A) {                // four 128x128 chunk-major, KC=16
      int t = i - OFF_W21;
      int m = t >> 14; t &= 16383;
      const float* src = (m == 0) ? w21 : (m == 1) ? w22 : (m == 2) ? wm1 : wm2;
      int j = t & 7, c = t >> 3, l16 = c & 15, t1 = c >> 4;
      int k8 = t1 & 15, mt = t1 >> 4;
      v = src[(mt * 16 + l16) * 128 + k8 * 8 + j] * SCL_TANH;
    } else {                                 // L4 A-frags, 2 chains
      int t = i - OFF_W4A;
      int j = t & 7, r = t >> 3, l16 = r & 15, q = r >> 4;
      int cc = q & 15, chain = q >> 4;
      int k = cc * 8 + j, m = l16;
      if (chain == 0) v = (m < 3) ? w31[m * 128 + k] : 0.f;
      else            v = (m < 2) ? w32[m * 128 + k] * SCL_SIG : 0.f;
    }
    ws[i] = (_Float16)v;
  }
  float* bws = (float*)(ws + OFF_BIAS);
  for (int i = blockIdx.x * blockDim.x + threadIdx.x; i < 640; i += stride) {
    int layer = i >> 7, idx = i & 127;
    const float* src = (layer == 0) ? b1 : (layer == 1) ? b21
                     : (layer == 2) ? b22 : (layer == 3) ? bm1 : bm2;
    bws[i] = src[idx] * SCL_TANH;
  }
}

// M32xN32 layer tile: wave owns 2 m-tiles (features [32wv,32wv+32)) x both
// n-tiles of the 32-sample block. B-frags reused across both m-tiles.
// Bias added post-MFMA; tanh fused; chunk-major LDS (RS=256).
__device__ __forceinline__ void layer2x2(const _Float16* __restrict__ wA,
                                         const float* __restrict__ bb,
                                         const _Float16* __restrict__ inB,
                                         _Float16* __restrict__ outB,
                                         int mg, int quad, int l16) {
  const int mt0 = mg * 2;
  half8 A[2][4];
#pragma unroll
  for (int mi = 0; mi < 2; ++mi)
#pragma unroll
    for (int kk = 0; kk < 4; ++kk)
      A[mi][kk] = *(const half8*)(wA + (((mt0 + mi) * 16 + kk * 4 + quad) * 16 + l16) * 8);
  float4_t bv[2];
  bv[0] = *(const float4_t*)(bb + (mt0 + 0) * 16 + quad * 4);
  bv[1] = *(const float4_t*)(bb + (mt0 + 1) * 16 + quad * 4);

  float4_t acc[2][2];
#pragma unroll
  for (int mi = 0; mi < 2; ++mi)
#pragma unroll
    for (int ni = 0; ni < 2; ++ni)
      acc[mi][ni] = (float4_t){0.f, 0.f, 0.f, 0.f};

#pragma unroll
  for (int ni = 0; ni < 2; ++ni) {
    half8 B[4];
#pragma unroll
    for (int kk = 0; kk < 4; ++kk)
      B[kk] = *(const half8*)(inB + (kk * 4 + quad) * RS + (ni * 16 + l16) * 8);
#pragma unroll
    for (int kk = 0; kk < 4; ++kk) {
      acc[0][ni] = __builtin_amdgcn_mfma_f32_16x16x32_f16(A[0][kk], B[kk], acc[0][ni], 0, 0, 0);
      acc[1][ni] = __builtin_amdgcn_mfma_f32_16x16x32_f16(A[1][kk], B[kk], acc[1][ni], 0, 0, 0);
    }
  }

#pragma unroll
  for (int mi = 0; mi < 2; ++mi) {
    const int ob = (mt0 + mi) * 16 + quad * 4;
    _Float16* base = outB + (ob >> 3) * RS + (ob & 7);
#pragma unroll
    for (int ni = 0; ni < 2; ++ni) {
      const int s = ni * 16 + l16;
      float4_t a = acc[mi][ni];
      half4_t h = pack4(tanh_pre(a[0] + bv[mi][0]), tanh_pre(a[1] + bv[mi][1]),
                        tanh_pre(a[2] + bv[mi][2]), tanh_pre(a[3] + bv[mi][3]));
      *(half4_t*)(base + s * 8) = h;
    }
  }
}

// Small-block 3-buffer / 5-phase schedule: SB=32, NT=256 (4 waves),
// LDS 24 KiB -> 6 blocks/CU (24 waves, 75% cap); barriers sync only 4 waves.
// __launch_bounds__ 2nd arg: empirically cap = floor(256/arg) VGPRs
// (R0/R1/R2/R5/R6: arg 6->40+spill, 4->64, 3->85, 2->128, 1->256).
// arg=4 -> 64-VGPR cap; kernel needs ~48 -> no spill; residency LDS-governed.
__global__ __launch_bounds__(NT, 4) void bnet_main(
    const float* __restrict__ x, const float* __restrict__ meang,
    const float* __restrict__ stdg, const float* __restrict__ b31,
    const float* __restrict__ b32, const _Float16* __restrict__ ws,
    float* __restrict__ out) {
  __shared__ __align__(16) _Float16 bufH[SB * 128];
  __shared__ __align__(16) _Float16 bufA[SB * 128];
  __shared__ __align__(16) _Float16 bufB[SB * 128];

  const int tid = threadIdx.x;
  const int wv = tid >> 6;          // 0..3 = m-group: features [32wv, 32wv+32)
  const int lane = tid & 63;
  const int quad = lane >> 4;
  const int l16 = lane & 15;
  const int s0 = blockIdx.x * SB;
  const float* biasF = (const float*)(ws + OFF_BIAS);

  // ---- L1: B built from global x (K=32 zero-padded), 2x2 tiles ----
  {
    half8 A1[2];
#pragma unroll
    for (int mi = 0; mi < 2; ++mi)
      A1[mi] = *(const half8*)(ws + OFF_W1 + (((wv * 2 + mi) * 4 + quad) * 16 + l16) * 8);
    float4_t bv1[2];
    bv1[0] = *(const float4_t*)(biasF + (wv * 2 + 0) * 16 + quad * 4);
    bv1[1] = *(const float4_t*)(biasF + (wv * 2 + 1) * 16 + quad * 4);

    half8 xb[2];
#pragma unroll
    for (int ni = 0; ni < 2; ++ni) {
#pragma unroll
      for (int j = 0; j < 8; ++j) xb[ni][j] = (_Float16)0.f;
      if (quad == 0) {
        const float* xp = x + (size_t)(s0 + ni * 16 + l16) * 6;
        float2_t e0 = *(const float2_t*)(xp);
        float2_t e1 = *(const float2_t*)(xp + 2);
        float2_t e2 = *(const float2_t*)(xp + 4);
        xb[ni][0] = (_Float16)e0[0]; xb[ni][1] = (_Float16)e0[1];
        xb[ni][2] = (_Float16)e1[0]; xb[ni][3] = (_Float16)e1[1];
        xb[ni][4] = (_Float16)e2[0]; xb[ni][5] = (_Float16)e2[1];
      }
    }
    float4_t acc[2][2];
#pragma unroll
    for (int mi = 0; mi < 2; ++mi)
#pragma unroll
      for (int ni = 0; ni < 2; ++ni) {
        acc[mi][ni] = (float4_t){0.f, 0.f, 0.f, 0.f};
        acc[mi][ni] = __builtin_amdgcn_mfma_f32_16x16x32_f16(A1[mi], xb[ni], acc[mi][ni], 0, 0, 0);
      }
#pragma unroll
    for (int mi = 0; mi < 2; ++mi) {
      const int ob = (wv * 2 + mi) * 16 + quad * 4;
      _Float16* base = bufH + (ob >> 3) * RS + (ob & 7);
#pragma unroll
      for (int ni = 0; ni < 2; ++ni) {
        const int s = ni * 16 + l16;
        float4_t a = acc[mi][ni];
        half4_t h = pack4(tanh_pre(a[0] + bv1[mi][0]), tanh_pre(a[1] + bv1[mi][1]),
                          tanh_pre(a[2] + bv1[mi][2]), tanh_pre(a[3] + bv1[mi][3]));
        *(half4_t*)(base + s * 8) = h;
      }
    }
  }
  __syncthreads();                                           // b1

  layer2x2(ws + OFF_W21, biasF + 128, bufH, bufA, wv, quad, l16);  // x21: H -> A
  layer2x2(ws + OFF_W22, biasF + 256, bufH, bufB, wv, quad, l16);  // x22: H -> B
  __syncthreads();                                           // b2 (H reads done)

  layer2x2(ws + OFF_WM1, biasF + 384, bufA, bufH, wv, quad, l16);  // xm1: A -> H
  half8 A4[2][4];                                            // prefetch L4 (waves 0-1)
  if (wv < 2) {
#pragma unroll
    for (int c = 0; c < 2; ++c)
#pragma unroll
      for (int kk = 0; kk < 4; ++kk)
        A4[c][kk] = *(const half8*)(ws + OFF_W4A +
                                    ((c * 16 + kk * 4 + quad) * 16 + l16) * 8);
  }
  __syncthreads();                                           // b3 (A reads done)

  layer2x2(ws + OFF_WM2, biasF + 512, bufB, bufA, wv, quad, l16);  // xm2: B -> A
  __syncthreads();                                           // b4

  // ---- L4 + QP epilogue: waves 0-1, one 16-sample n-tile each, both chains ----
  if (wv < 2) {
    const int nt = wv;
    float4_t c0 = (float4_t){0.f, 0.f, 0.f, 0.f};
    float4_t c1 = (float4_t){0.f, 0.f, 0.f, 0.f};
    if (quad == 0) {
      c0[0] = b31[0]; c0[1] = b31[1]; c0[2] = b31[2];
      c1[0] = b32[0] * SCL_SIG; c1[1] = b32[1] * SCL_SIG;
    }
#pragma unroll
    for (int kk = 0; kk < 4; ++kk) {
      half8 bh = *(const half8*)(bufH + (kk * 4 + quad) * RS + (nt * 16 + l16) * 8);
      half8 bc = *(const half8*)(bufA + (kk * 4 + quad) * RS + (nt * 16 + l16) * 8);
      c0 = __builtin_amdgcn_mfma_f32_16x16x32_f16(A4[0][kk], bh, c0, 0, 0, 0);
      c1 = __builtin_amdgcn_mfma_f32_16x16x32_f16(A4[1][kk], bc, c1, 0, 0, 0);
    }
    if (quad == 0) {   // rows 0..3 live in lanes 0-15, regs 0-3
      const int s = nt * 16 + l16;
      float u0 = -c0[0];
      float u1 = -c0[1];
      float u2 = -c0[2];
      float p0 = 4.f * __builtin_amdgcn_rcpf(1.f + __builtin_amdgcn_exp2f(c1[0]));
      float p1 = 4.f * __builtin_amdgcn_rcpf(1.f + __builtin_amdgcn_exp2f(c1[1]));
      const float m0 = meang[0], m1 = meang[1], m2 = meang[2];
      const float m3 = meang[3], m4 = meang[4], m5 = meang[5];
      const float sd0 = stdg[0], sd1 = stdg[1], sd2 = stdg[2];
      const float sd3 = stdg[3], sd4 = stdg[4], sd5 = stdg[5];
      const float* xp = x + (size_t)(s0 + s) * 6;
      float2_t e0 = *(const float2_t*)(xp);
      float2_t e1 = *(const float2_t*)(xp + 2);
      float2_t e2 = *(const float2_t*)(xp + 4);
      float px = e0[0] * sd0 + m0, vx = e0[1] * sd1 + m1;
      float py = e1[0] * sd2 + m2, vy = e1[1] * sd3 + m3;
      float pz = e2[0] * sd4 + m4, vz = e2[1] * sd5 + m5;
      float dx = px - 10.f, dy = py - 10.f, dz = pz - 9.f;
      float dx2 = dx * dx, dy2 = dy * dy, dz2 = dz * dz;
      float dx3 = dx2 * dx, dy3 = dy2 * dy, dz3 = dz2 * dz;
      float barrier = dx3 * dx + dy3 * dy + dz3 * dz - 2401.f;  // R^4
      float bdot = 4.f * (dx3 * vx + dy3 * vy + dz3 * vz);
      float Lf2b = 12.f * (dx2 * vx * vx + dy2 * vy * vy + dz2 * vz * vz);
      float g0 = -4.f * dx3, g1 = -4.f * dy3, g2 = -4.f * dz3;
      float hv = Lf2b + (p0 + p1) * bdot + p0 * p1 * barrier;
      float Gu = g0 * u0 + g1 * u1 + g2 * u2;
      float GG = g0 * g0 + g1 * g1 + g2 * g2;
      float lam = fmaxf(Gu - hv, 0.f) / GG;
      float* op = out + (size_t)(s0 + s) * 3;
      op[0] = u0 - lam * g0;
      op[1] = u1 - lam * g1;
      op[2] = u2 - lam * g2;
    }
  }
}

extern "C" void kernel_launch(void* const* d_in, const int* in_sizes, int n_in,
                              void* d_out, int out_size, void* d_ws, size_t ws_size,
                              hipStream_t stream) {
  const float* x    = (const float*)d_in[0];
  const float* mean = (const float*)d_in[1];
  const float* stdv = (const float*)d_in[2];
  const float* w1   = (const float*)d_in[3];
  const float* b1   = (const float*)d_in[4];
  const float* w21  = (const float*)d_in[5];
  const float* b21  = (const float*)d_in[6];
  const float* w22  = (const float*)d_in[7];
  const float* b22  = (const float*)d_in[8];
  const float* wm1  = (const float*)d_in[9];
  const float* bm1  = (const float*)d_in[10];
  const float* wm2  = (const float*)d_in[11];
  const float* bm2  = (const float*)d_in[12];
  const float* w31  = (const float*)d_in[13];
  const float* b31  = (const float*)d_in[14];
  const float* w32  = (const float*)d_in[15];
  const float* b32  = (const float*)d_in[16];
  _Float16* ws = (_Float16*)d_ws;
  float* out = (float*)d_out;
  const int batch = in_sizes[0] / 6;

  hipLaunchKernelGGL(prepack, dim3(96), dim3(256), 0, stream,
                     w1, w21, w22, wm1, wm2, w31, w32,
                     b1, b21, b22, bm1, bm2, ws);
  hipLaunchKernelGGL(bnet_main, dim3(batch / SB), dim3(NT), 0, stream,
                     x, mean, stdv, b31, b32, (const _Float16*)ws, out);
}